// Round 6
// baseline (329.199 us; speedup 1.0000x reference)
//
#include <hip/hip_runtime.h>
#include <stdint.h>

typedef __attribute__((ext_vector_type(8))) short short8;
typedef __attribute__((ext_vector_type(4))) float f32x4;
typedef __attribute__((ext_vector_type(4))) float float4v;
typedef __attribute__((ext_vector_type(4))) unsigned short u16x4;
typedef __attribute__((ext_vector_type(8))) unsigned short u16x8;

#define AS1 __attribute__((address_space(1)))
#define AS3 __attribute__((address_space(3)))

// B=4, C=512, Lf=8192, A=6. N = 49152.
// d_out: obj [4][49152] @0, reg [4][49152][2] @196608, anchors [49152][2] @589824.
// ws layout (bytes):
//   wAf   @ 0        : bf16 pre-fragmented conv weights, chunk id =
//                      (cb*3+t)*16+kc, 512 elems/chunk, lane i of chunk holds
//                      A[cout=cb*16+(i&15)][cin=kc*32+(i>>4)*8 .. +8]  (1,572,864)
//   hwp   @ 1572864  : bf16 [32][512], rows 0-5 obj_w, 6-17 reg_w, rest 0 (32,768)
//   featT @ 1605632  : bf16 [4][8208][512], row r holds l=r-1;
//                      rows 0 and 8193 zeroed (SAME pad); slop rows 8194+ of
//                      b=3 host the group counters (row 8200 = 256 uint32)
//   part  @ 35225600 : fp32 [4 mblk][4 b][8192 l][18 j] head partials (9,437,184)

__device__ __forceinline__ unsigned short f2bf(float f) {
    union { float f; unsigned int u; } v; v.f = f;
    unsigned int r = v.u + 0x7fffu + ((v.u >> 16) & 1u);
    return (unsigned short)(r >> 16);
}

__constant__ float c_AL[6] = {2.f, 4.f, 6.f, 9.f, 13.f, 18.f};

// blocks [0,4096): 64x64 transpose tiles.  blocks [4096,7441): prep work.
__global__ __launch_bounds__(256) void prep_transpose_kernel(
    const float* __restrict__ feat, const float* __restrict__ conv_w,
    const float* __restrict__ obj_w, const float* __restrict__ reg_w,
    unsigned short* __restrict__ wAf, unsigned short* __restrict__ hwp,
    unsigned short* __restrict__ featT, unsigned int* __restrict__ cnt,
    float* __restrict__ out) {
    __shared__ unsigned short tile[64][68];   // bf16 [c][l], pad 68
    unsigned int bx = blockIdx.x;
    int tid = threadIdx.x;
    if (bx < 4096u) {
        int l0 = (bx & 127) * 64, c0 = ((bx >> 7) & 7) * 64, b = bx >> 10;
        const float* fb = feat + ((size_t)b * 512 + c0) * 8192 + l0;
        #pragma unroll
        for (int it = 0; it < 4; ++it) {
            int slot = it * 256 + tid;
            int c = slot >> 4, l4 = (slot & 15) << 2;
            float4v v = *(const float4v*)(fb + (size_t)c * 8192 + l4);
            u16x4 pk;
            pk.x = f2bf(v.x); pk.y = f2bf(v.y);
            pk.z = f2bf(v.z); pk.w = f2bf(v.w);
            *(u16x4*)(&tile[c][l4]) = pk;
        }
        __syncthreads();
        unsigned short* ftb = featT + ((size_t)b * 8208 + 1 + l0) * 512 + c0;
        #pragma unroll
        for (int it = 0; it < 2; ++it) {
            int slot = it * 256 + tid;
            int l = slot >> 3, c8 = (slot & 7) << 3;
            u16x8 pk;
            #pragma unroll
            for (int j = 0; j < 8; ++j) pk[j] = tile[c8 + j][l];
            *(u16x8*)(ftb + (size_t)l * 512 + c8) = pk;
        }
        return;
    }
    unsigned int idx = (bx - 4096u) * 256 + tid;
    if (idx < 786432u) {
        // fragment-major conv weights
        unsigned int chunkid = idx >> 9;            // 0..1535
        unsigned int within = idx & 511u;
        unsigned int lane = within >> 3, j = within & 7u;
        unsigned int kc = chunkid & 15u;
        unsigned int ct = chunkid >> 4;             // cb*3 + t
        unsigned int t = ct % 3u, cb = ct / 3u;
        unsigned int cout = cb * 16u + (lane & 15u);
        unsigned int cin = kc * 32u + (lane >> 4) * 8u + j;
        wAf[idx] = f2bf(conv_w[(cout * 512u + cin) * 3u + t]);
    } else if (idx < 802816u) {
        unsigned int i2 = idx - 786432u;
        unsigned int j = i2 >> 9, c = i2 & 511u;
        float v = 0.f;
        if (j < 6u) v = obj_w[j * 512u + c];
        else if (j < 18u) v = reg_w[(j - 6u) * 512u + c];
        hwp[i2] = f2bf(v);
    } else if (idx < 851968u) {
        unsigned int n = idx - 802816u;
        unsigned int l = n / 6u, a = n - l * 6u;
        float ctr = (float)l + 0.5f, half = 0.5f * c_AL[a];
        float* anchors = out + 589824;
        anchors[2 * n]     = ctr - half;
        anchors[2 * n + 1] = ctr + half;
    } else if (idx < 856064u) {
        unsigned int i4 = idx - 851968u;
        unsigned int b = i4 >> 10, rem = i4 & 1023u;
        unsigned int row = (rem >> 9) ? 8193u : 0u;
        unsigned int c = rem & 511u;
        featT[((size_t)b * 8208 + row) * 512 + c] = 0;
    } else if (idx < 856320u) {
        cnt[idx - 856064u] = 0u;                    // group counters
    }
}

// Conv GEMM: per block, 128 couts x 128 l's, K = 3 taps * 512 cin.
// Fragment-major LDS for A and B: every ds_read_b128 is base + lane*16B
// (conflict-free). Epilogue: bias+relu -> bf16 htile in LDS, fused heads
// mini-GEMM -> per-mblock partials; the LAST of the 4 m-blocks per (x,z)
// group (device-scope counter) reduces the partials and writes final
// obj/reg with bias. launch_bounds(256,4): 4 blocks/CU, grid 1024 = 4/CU.
__global__ __launch_bounds__(256, 4) void conv_gemm_kernel(
    const unsigned short* __restrict__ wAf,
    const unsigned short* __restrict__ featT,
    const float* __restrict__ conv_b,
    const unsigned short* __restrict__ hwp,
    const float* __restrict__ obj_b,
    const float* __restrict__ reg_b,
    float* __restrict__ part,
    unsigned int* __restrict__ cnt,
    float* __restrict__ out) {
    __shared__ unsigned short smem[17408];  // loop: 33*512 staging; epi: htile 128*136

    const int tid = threadIdx.x;
    const int wave = tid >> 6, lane = tid & 63;
    const int lq = lane >> 4, lr = lane & 15;
    const int l0 = blockIdx.x * 128;
    const int m0 = blockIdx.y * 128;
    const int b = blockIdx.z;
    const int wm = wave >> 1, wn = wave & 1;
    const unsigned short* ftb = featT + (size_t)b * 8208 * 512;

    f32x4 acc[4][4];
    #pragma unroll
    for (int i = 0; i < 4; ++i)
        #pragma unroll
        for (int j = 0; j < 4; ++j)
            acc[i][j] = (f32x4){0.f, 0.f, 0.f, 0.f};

    for (int kc = 0; kc < 16; ++kc) {
        __syncthreads();
        // 33 chunks of 1024B: 24 A-chunks (fragment-major wAf) + 9 B-chunks
        for (int ci = wave; ci < 33; ci += 4) {
            const unsigned short* g;
            if (ci < 24) {
                int t = ci >> 3, rb = ci & 7;
                g = wAf + ((size_t)(((m0 >> 4) + rb) * 3 + t) * 16 + kc) * 512 + lane * 8;
            } else {
                int lb = ci - 24;
                g = ftb + (size_t)(l0 + lb * 16 + lr) * 512 + kc * 32 + lq * 8;
            }
            __builtin_amdgcn_global_load_lds((const AS1 void*)g,
                                             (AS3 void*)(smem + ci * 512), 16, 0, 0);
        }
        __syncthreads();
        #pragma unroll
        for (int t = 0; t < 3; ++t) {
            short8 af[4], bf[4];
            #pragma unroll
            for (int fm = 0; fm < 4; ++fm)
                af[fm] = *(const short8*)(smem + ((t * 8 + wm * 4 + fm) << 9) + (lane << 3));
            #pragma unroll
            for (int fn = 0; fn < 4; ++fn) {
                int R = wn * 64 + fn * 16 + lr + t;   // tap-shifted B row
                bf[fn] = *(const short8*)(smem + ((24 + (R >> 4)) << 9) +
                                          ((((lq << 4) | (R & 15))) << 3));
            }
            #pragma unroll
            for (int fm = 0; fm < 4; ++fm)
                #pragma unroll
                for (int fn = 0; fn < 4; ++fn)
                    acc[fm][fn] = __builtin_amdgcn_mfma_f32_16x16x32_bf16(
                        af[fm], bf[fn], acc[fm][fn], 0, 0, 0);
        }
    }
    __syncthreads();
    // epilogue 1: bias + relu -> bf16 htile [l=n][c=cout], row stride 136
    #pragma unroll
    for (int fm = 0; fm < 4; ++fm) {
        int mb = wm * 64 + fm * 16 + lq * 4;
        float cb0 = conv_b[m0 + mb];
        float cb1 = conv_b[m0 + mb + 1];
        float cb2 = conv_b[m0 + mb + 2];
        float cb3 = conv_b[m0 + mb + 3];
        #pragma unroll
        for (int fn = 0; fn < 4; ++fn) {
            int n = wn * 64 + fn * 16 + lr;
            f32x4 v = acc[fm][fn];
            u16x4 pk;
            pk.x = f2bf(fmaxf(v.x + cb0, 0.f));
            pk.y = f2bf(fmaxf(v.y + cb1, 0.f));
            pk.z = f2bf(fmaxf(v.z + cb2, 0.f));
            pk.w = f2bf(fmaxf(v.w + cb3, 0.f));
            *(u16x4*)(smem + n * 136 + mb) = pk;
        }
    }
    __syncthreads();
    // epilogue 2: fused heads. Per wave: 32 l's x 32 j's x K=128 local couts.
    f32x4 hacc[2][2];
    #pragma unroll
    for (int i = 0; i < 2; ++i) {
        hacc[i][0] = (f32x4){0.f, 0.f, 0.f, 0.f};
        hacc[i][1] = (f32x4){0.f, 0.f, 0.f, 0.f};
    }
    const int lbase = wave * 32;
    for (int kk = 0; kk < 4; ++kk) {
        short8 ha[2], hb2[2];
        #pragma unroll
        for (int fm2 = 0; fm2 < 2; ++fm2)
            ha[fm2] = *(const short8*)(smem + (lbase + fm2 * 16 + lr) * 136 + kk * 32 + lq * 8);
        #pragma unroll
        for (int fn = 0; fn < 2; ++fn)
            hb2[fn] = *(const short8*)(hwp + (size_t)(fn * 16 + lr) * 512 + m0 + kk * 32 + lq * 8);
        #pragma unroll
        for (int fm2 = 0; fm2 < 2; ++fm2)
            #pragma unroll
            for (int fn = 0; fn < 2; ++fn)
                hacc[fm2][fn] = __builtin_amdgcn_mfma_f32_16x16x32_bf16(
                    ha[fm2], hb2[fn], hacc[fm2][fn], 0, 0, 0);
    }
    // partials store: part[mblk=by][b][l][j]
    float* pb = part + ((size_t)(blockIdx.y * 4 + b) * 8192) * 18;
    #pragma unroll
    for (int fn = 0; fn < 2; ++fn) {
        int j = fn * 16 + lr;
        if (j >= 18) continue;
        #pragma unroll
        for (int fm2 = 0; fm2 < 2; ++fm2)
            #pragma unroll
            for (int r = 0; r < 4; ++r) {
                int l = l0 + lbase + fm2 * 16 + lq * 4 + r;
                pb[(size_t)l * 18 + j] = hacc[fm2][fn][r];
            }
    }
    // ---- last-block-done reduction for this (x, z) group ----
    __threadfence();          // release our partials device-wide
    __syncthreads();          // all threads' stores+fences done
    volatile unsigned int* flag = (volatile unsigned int*)smem;
    if (tid == 0)
        *flag = atomicAdd(&cnt[blockIdx.x * 4 + b], 1u);
    __syncthreads();
    if (*flag == 3u) {        // we are the 4th m-block: reduce + write out
        __threadfence();      // acquire: see siblings' partials
        float* outObj = out + (size_t)b * 49152;
        float* outReg = out + 196608 + (size_t)b * 98304;
        for (int i = tid; i < 2304; i += 256) {
            int l = l0 + i / 18;
            int j = i - (i / 18) * 18;
            float s = 0.f;
            #pragma unroll
            for (int mb = 0; mb < 4; ++mb)
                s += part[((size_t)(mb * 4 + b) * 8192 + l) * 18 + j];
            if (j < 6) outObj[l * 6 + j] = s + obj_b[j];
            else outReg[l * 12 + (j - 6)] = s + reg_b[j - 6];
        }
    }
}

extern "C" void kernel_launch(void* const* d_in, const int* in_sizes, int n_in,
                              void* d_out, int out_size, void* d_ws, size_t ws_size,
                              hipStream_t stream) {
    const float* feat   = (const float*)d_in[0];
    const float* conv_w = (const float*)d_in[1];
    const float* conv_b = (const float*)d_in[2];
    const float* obj_w  = (const float*)d_in[3];
    const float* obj_b  = (const float*)d_in[4];
    const float* reg_w  = (const float*)d_in[5];
    const float* reg_b  = (const float*)d_in[6];
    float* out = (float*)d_out;
    char* ws = (char*)d_ws;
    unsigned short* wAf   = (unsigned short*)(ws);
    unsigned short* hwp   = (unsigned short*)(ws + 1572864);
    unsigned short* featT = (unsigned short*)(ws + 1605632);
    float* part           = (float*)(ws + 35225600);
    // counters live in featT slop: b=3, row 8200 (never written by transpose,
    // staged-but-unused by conv MFMA)
    unsigned int* cnt = (unsigned int*)(featT + ((size_t)3 * 8208 + 8200) * 512);

    prep_transpose_kernel<<<dim3(7441), dim3(256), 0, stream>>>(
        feat, conv_w, obj_w, reg_w, wAf, hwp, featT, cnt, out);
    conv_gemm_kernel<<<dim3(64, 4, 4), dim3(256), 0, stream>>>(
        wAf, featT, conv_b, hwp, obj_b, reg_b, part, cnt, out);
}

// Round 7
// 170.094 us; speedup vs baseline: 1.9354x; 1.9354x over previous
//
#include <hip/hip_runtime.h>
#include <stdint.h>

typedef __attribute__((ext_vector_type(8))) short short8;
typedef __attribute__((ext_vector_type(4))) float f32x4;
typedef __attribute__((ext_vector_type(4))) float float4v;
typedef __attribute__((ext_vector_type(4))) unsigned short u16x4;
typedef __attribute__((ext_vector_type(8))) unsigned short u16x8;

#define AS1 __attribute__((address_space(1)))
#define AS3 __attribute__((address_space(3)))

// B=4, C=512, Lf=8192, A=6. N = 49152.
// d_out: obj [4][49152] @0, reg [4][49152][2] @196608, anchors [49152][2] @589824.
// ws layout (bytes):
//   wAf   @ 0        : bf16 pre-fragmented conv weights, chunk id =
//                      (cb*3+t)*16+kc, 512 elems/chunk, lane i of chunk holds
//                      A[cout=cb*16+(i&15)][cin=kc*32+(i>>4)*8 .. +8]  (1,572,864)
//   hwp   @ 1572864  : bf16 [32][512], rows 0-5 obj_w, 6-17 reg_w, rest 0 (32,768)
//   featT @ 1605632  : bf16 [4][8208][512], row r holds l=r-1;
//                      rows 0 and 8193 zeroed (SAME pad), 8194+ slop (33,619,968)
//   part  @ 35225600 : fp32 [4 mblk][4 b][8192 l][18 j] head partials (9,437,184)

__device__ __forceinline__ unsigned short f2bf(float f) {
    union { float f; unsigned int u; } v; v.f = f;
    unsigned int r = v.u + 0x7fffu + ((v.u >> 16) & 1u);
    return (unsigned short)(r >> 16);
}

__constant__ float c_AL[6] = {2.f, 4.f, 6.f, 9.f, 13.f, 18.f};

__global__ __launch_bounds__(256) void prep_kernel(
    const float* __restrict__ conv_w, const float* __restrict__ obj_w,
    const float* __restrict__ reg_w, unsigned short* __restrict__ wAf,
    unsigned short* __restrict__ hwp, unsigned short* __restrict__ featT,
    float* __restrict__ out) {
    unsigned int idx = blockIdx.x * 256 + threadIdx.x;
    if (idx < 786432u) {
        // fragment-major conv weights for 16x16x32 MFMA
        unsigned int chunkid = idx >> 9;            // 0..1535
        unsigned int within = idx & 511u;
        unsigned int lane = within >> 3, j = within & 7u;
        unsigned int kc = chunkid & 15u;
        unsigned int ct = chunkid >> 4;             // cb*3 + t
        unsigned int t = ct % 3u, cb = ct / 3u;
        unsigned int cout = cb * 16u + (lane & 15u);
        unsigned int cin = kc * 32u + (lane >> 4) * 8u + j;
        wAf[idx] = f2bf(conv_w[(cout * 512u + cin) * 3u + t]);
    } else if (idx < 802816u) {
        unsigned int i2 = idx - 786432u;
        unsigned int j = i2 >> 9, c = i2 & 511u;
        float v = 0.f;
        if (j < 6u) v = obj_w[j * 512u + c];
        else if (j < 18u) v = reg_w[(j - 6u) * 512u + c];
        hwp[i2] = f2bf(v);
    } else if (idx < 851968u) {
        unsigned int n = idx - 802816u;
        unsigned int l = n / 6u, a = n - l * 6u;
        float ctr = (float)l + 0.5f, half = 0.5f * c_AL[a];
        float* anchors = out + 589824;
        anchors[2 * n]     = ctr - half;
        anchors[2 * n + 1] = ctr + half;
    } else if (idx < 856064u) {
        unsigned int i4 = idx - 851968u;
        unsigned int b = i4 >> 10, rem = i4 & 1023u;
        unsigned int row = (rem >> 9) ? 8193u : 0u;
        unsigned int c = rem & 511u;
        featT[((size_t)b * 8208 + row) * 512 + c] = 0;
    }
}

__global__ __launch_bounds__(256) void transpose_kernel(
    const float* __restrict__ feat, unsigned short* __restrict__ featT) {
    __shared__ unsigned short tile[64][68];   // bf16 [c][l], pad 68
    int tid = threadIdx.x;
    int l0 = blockIdx.x * 64, c0 = blockIdx.y * 64, b = blockIdx.z;
    const float* fb = feat + ((size_t)b * 512 + c0) * 8192 + l0;
    #pragma unroll
    for (int it = 0; it < 4; ++it) {
        int slot = it * 256 + tid;
        int c = slot >> 4, l4 = (slot & 15) << 2;
        float4v v = *(const float4v*)(fb + (size_t)c * 8192 + l4);
        u16x4 pk;
        pk.x = f2bf(v.x); pk.y = f2bf(v.y);
        pk.z = f2bf(v.z); pk.w = f2bf(v.w);
        *(u16x4*)(&tile[c][l4]) = pk;
    }
    __syncthreads();
    unsigned short* ftb = featT + ((size_t)b * 8208 + 1 + l0) * 512 + c0;
    #pragma unroll
    for (int it = 0; it < 2; ++it) {
        int slot = it * 256 + tid;
        int l = slot >> 3, c8 = (slot & 7) << 3;
        u16x8 pk;
        #pragma unroll
        for (int j = 0; j < 8; ++j) pk[j] = tile[c8 + j][l];
        *(u16x8*)(ftb + (size_t)l * 512 + c8) = pk;
    }
}

// Conv GEMM: per block, 128 couts x 128 l's, K = 3 taps * 512 cin.
// Fragment-major LDS for A and B: every ds_read_b128 is base + lane*16B
// (conflict-free). Epilogue: bias+relu -> bf16 htile in LDS, fused heads
// mini-GEMM -> per-mblock partials in ws (atomic-free, reduced later).
// launch_bounds(256,4): 4 blocks/CU resident (LDS 4*34816=139KB<=160KB),
// grid 1024 = exactly 4/CU -> single round, no straggler tail.
// NOTE (R6 lesson): NO device-scope fences/atomics in this kernel — a single
// __threadfence per block collapsed MfmaUtil 38%->9% (L2 writeback storm).
__global__ __launch_bounds__(256, 4) void conv_gemm_kernel(
    const unsigned short* __restrict__ wAf,
    const unsigned short* __restrict__ featT,
    const float* __restrict__ conv_b,
    const unsigned short* __restrict__ hwp,
    float* __restrict__ part) {
    __shared__ unsigned short smem[17408];  // loop: 33*512 staging; epi: htile 128*136

    const int tid = threadIdx.x;
    const int wave = tid >> 6, lane = tid & 63;
    const int lq = lane >> 4, lr = lane & 15;
    const int l0 = blockIdx.x * 128;
    const int m0 = blockIdx.y * 128;
    const int b = blockIdx.z;
    const int wm = wave >> 1, wn = wave & 1;
    const unsigned short* ftb = featT + (size_t)b * 8208 * 512;

    f32x4 acc[4][4];
    #pragma unroll
    for (int i = 0; i < 4; ++i)
        #pragma unroll
        for (int j = 0; j < 4; ++j)
            acc[i][j] = (f32x4){0.f, 0.f, 0.f, 0.f};

    for (int kc = 0; kc < 16; ++kc) {
        __syncthreads();
        // 33 chunks of 1024B: 24 A-chunks (fragment-major wAf) + 9 B-chunks
        for (int ci = wave; ci < 33; ci += 4) {
            const unsigned short* g;
            if (ci < 24) {
                int t = ci >> 3, rb = ci & 7;
                g = wAf + ((size_t)(((m0 >> 4) + rb) * 3 + t) * 16 + kc) * 512 + lane * 8;
            } else {
                int lb = ci - 24;
                g = ftb + (size_t)(l0 + lb * 16 + lr) * 512 + kc * 32 + lq * 8;
            }
            __builtin_amdgcn_global_load_lds((const AS1 void*)g,
                                             (AS3 void*)(smem + ci * 512), 16, 0, 0);
        }
        __syncthreads();
        #pragma unroll
        for (int t = 0; t < 3; ++t) {
            short8 af[4], bf[4];
            #pragma unroll
            for (int fm = 0; fm < 4; ++fm)
                af[fm] = *(const short8*)(smem + ((t * 8 + wm * 4 + fm) << 9) + (lane << 3));
            #pragma unroll
            for (int fn = 0; fn < 4; ++fn) {
                int R = wn * 64 + fn * 16 + lr + t;   // tap-shifted B row
                bf[fn] = *(const short8*)(smem + ((24 + (R >> 4)) << 9) +
                                          ((((lq << 4) | (R & 15))) << 3));
            }
            #pragma unroll
            for (int fm = 0; fm < 4; ++fm)
                #pragma unroll
                for (int fn = 0; fn < 4; ++fn)
                    acc[fm][fn] = __builtin_amdgcn_mfma_f32_16x16x32_bf16(
                        af[fm], bf[fn], acc[fm][fn], 0, 0, 0);
        }
    }
    __syncthreads();
    // epilogue 1: bias + relu -> bf16 htile [l=n][c=cout], row stride 136
    #pragma unroll
    for (int fm = 0; fm < 4; ++fm) {
        int mb = wm * 64 + fm * 16 + lq * 4;
        float cb0 = conv_b[m0 + mb];
        float cb1 = conv_b[m0 + mb + 1];
        float cb2 = conv_b[m0 + mb + 2];
        float cb3 = conv_b[m0 + mb + 3];
        #pragma unroll
        for (int fn = 0; fn < 4; ++fn) {
            int n = wn * 64 + fn * 16 + lr;
            f32x4 v = acc[fm][fn];
            u16x4 pk;
            pk.x = f2bf(fmaxf(v.x + cb0, 0.f));
            pk.y = f2bf(fmaxf(v.y + cb1, 0.f));
            pk.z = f2bf(fmaxf(v.z + cb2, 0.f));
            pk.w = f2bf(fmaxf(v.w + cb3, 0.f));
            *(u16x4*)(smem + n * 136 + mb) = pk;
        }
    }
    __syncthreads();
    // epilogue 2: fused heads. Per wave: 32 l's x 32 j's x K=128 local couts.
    f32x4 hacc[2][2];
    #pragma unroll
    for (int i = 0; i < 2; ++i) {
        hacc[i][0] = (f32x4){0.f, 0.f, 0.f, 0.f};
        hacc[i][1] = (f32x4){0.f, 0.f, 0.f, 0.f};
    }
    const int lbase = wave * 32;
    for (int kk = 0; kk < 4; ++kk) {
        short8 ha[2], hb2[2];
        #pragma unroll
        for (int fm2 = 0; fm2 < 2; ++fm2)
            ha[fm2] = *(const short8*)(smem + (lbase + fm2 * 16 + lr) * 136 + kk * 32 + lq * 8);
        #pragma unroll
        for (int fn = 0; fn < 2; ++fn)
            hb2[fn] = *(const short8*)(hwp + (size_t)(fn * 16 + lr) * 512 + m0 + kk * 32 + lq * 8);
        #pragma unroll
        for (int fm2 = 0; fm2 < 2; ++fm2)
            #pragma unroll
            for (int fn = 0; fn < 2; ++fn)
                hacc[fm2][fn] = __builtin_amdgcn_mfma_f32_16x16x32_bf16(
                    ha[fm2], hb2[fn], hacc[fm2][fn], 0, 0, 0);
    }
    // partials store: part[mblk=by][b][l][j]
    float* pb = part + ((size_t)(blockIdx.y * 4 + b) * 8192) * 18;
    #pragma unroll
    for (int fn = 0; fn < 2; ++fn) {
        int j = fn * 16 + lr;
        if (j >= 18) continue;
        #pragma unroll
        for (int fm2 = 0; fm2 < 2; ++fm2)
            #pragma unroll
            for (int r = 0; r < 4; ++r) {
                int l = l0 + lbase + fm2 * 16 + lq * 4 + r;
                pb[(size_t)l * 18 + j] = hacc[fm2][fn][r];
            }
    }
}

__global__ __launch_bounds__(256) void reduce_kernel(
    const float* __restrict__ part, const float* __restrict__ obj_b,
    const float* __restrict__ reg_b, float* __restrict__ out) {
    unsigned int idx = blockIdx.x * 256 + threadIdx.x;
    if (idx >= 589824u) return;
    unsigned int j = idx % 18u;
    unsigned int t = idx / 18u;
    unsigned int l = t & 8191u;
    unsigned int b = t >> 13;
    float s = 0.f;
    #pragma unroll
    for (int mb = 0; mb < 4; ++mb)
        s += part[((size_t)(mb * 4 + b) * 8192 + l) * 18 + j];
    if (j < 6u) {
        s += obj_b[j];
        out[(size_t)b * 49152 + l * 6 + j] = s;
    } else {
        s += reg_b[j - 6u];
        out[196608u + (size_t)b * 98304 + l * 12 + (j - 6u)] = s;
    }
}

extern "C" void kernel_launch(void* const* d_in, const int* in_sizes, int n_in,
                              void* d_out, int out_size, void* d_ws, size_t ws_size,
                              hipStream_t stream) {
    const float* feat   = (const float*)d_in[0];
    const float* conv_w = (const float*)d_in[1];
    const float* conv_b = (const float*)d_in[2];
    const float* obj_w  = (const float*)d_in[3];
    const float* obj_b  = (const float*)d_in[4];
    const float* reg_w  = (const float*)d_in[5];
    const float* reg_b  = (const float*)d_in[6];
    float* out = (float*)d_out;
    char* ws = (char*)d_ws;
    unsigned short* wAf   = (unsigned short*)(ws);
    unsigned short* hwp   = (unsigned short*)(ws + 1572864);
    unsigned short* featT = (unsigned short*)(ws + 1605632);
    float* part           = (float*)(ws + 35225600);

    prep_kernel<<<dim3(3344), dim3(256), 0, stream>>>(conv_w, obj_w, reg_w,
                                                      wAf, hwp, featT, out);
    transpose_kernel<<<dim3(128, 8, 4), dim3(256), 0, stream>>>(feat, featT);
    conv_gemm_kernel<<<dim3(64, 4, 4), dim3(256), 0, stream>>>(wAf, featT, conv_b, hwp, part);
    reduce_kernel<<<dim3(2304), dim3(256), 0, stream>>>(part, obj_b, reg_b, out);
}